// Round 18
// baseline (106.654 us; speedup 1.0000x reference)
//
#include <hip/hip_runtime.h>
#include <math.h>

typedef _Float16 half8 __attribute__((ext_vector_type(8)));
typedef float f32x4 __attribute__((ext_vector_type(4)));

// dims
constexpr int B_ = 8;
constexpr int HG = 160, WG = 320;          // guidance spatial
constexpr int H = 80, W = 160;             // x spatial
// ws layout (bytes)
constexpr size_t CWS_OFF  = 0;             // 4 ng * 165888 = 663552
constexpr size_t W1WS_OFF = 663552;        // 9 taps * 4096 = 36864
constexpr size_t XG_OFF   = 700416;        // 8*80*160*64*2 = 13107200

// ---------------------------------------------------------------------------
// prep (REWRITTEN): one thread per 16-B fragment slot -> fully coalesced
// half8 stores (was: 9 scattered 2-B stores per thread).
// conv2 slot (ng,s,k,l): lane l = grp*16+nl holds w2 elements
//   kl = grp*8+j (j=0..7), cin = (s&1)*32+kl, t = s>>1, n = k*64+ng*16+nl
//   at byte l*16 + j*2 of fragment (s*9+k) in Cws[ng] — identical bytes to
//   the R8 layout (fragoff = (grp*16+nl)*16 + j*2).
// conv1 slot (t,nt,l): cin = grp*8+j, ch = nt*16+nl; byte nt*1024 + l*16+j*2
//   of w1ws[t] — identical to R8.
// ---------------------------------------------------------------------------
__global__ __launch_bounds__(256) void prep(const float* __restrict__ w1,
                                            const float* __restrict__ w2,
                                            char* __restrict__ ws)
{
    int e = blockIdx.x * 256 + threadIdx.x;
    if (e < 4 * 18 * 9 * 64) {
        int l  = e & 63;
        int r  = e >> 6;           // (ng*18 + s)*9 + k
        int k  = r % 9;
        int s  = (r / 9) % 18;
        int ng = r / (9 * 18);
        int grp = l >> 4, nl = l & 15;
        int t = s >> 1, c5 = s & 1;
        int n = k * 64 + ng * 16 + nl;
        const float* src = w2 + ((size_t)n * 64 + c5 * 32 + grp * 8) * 9 + t;
        half8 v;
#pragma unroll
        for (int j = 0; j < 8; ++j) v[j] = (_Float16)src[j * 9];
        *(half8*)(ws + CWS_OFF + (size_t)ng * 165888
                  + (size_t)(s * 9 + k) * 1024 + l * 16) = v;
    } else if (e < 4 * 18 * 9 * 64 + 9 * 4 * 64) {
        int e2 = e - 4 * 18 * 9 * 64;
        int l  = e2 & 63;
        int nt = (e2 >> 6) & 3;
        int t  = e2 >> 8;
        int grp = l >> 4, nl = l & 15;
        int ch = nt * 16 + nl;
        const float* src = w1 + ((size_t)ch * 32 + grp * 8) * 9 + t;
        half8 v;
#pragma unroll
        for (int j = 0; j < 8; ++j) v[j] = (_Float16)src[j * 9];
        *(half8*)(ws + W1WS_OFF + (size_t)t * 4096 + nt * 1024 + l * 16) = v;
    }
}

// ---------------------------------------------------------------------------
// conv1 (3x3 s2 p1, 32->64) + BN + ReLU via MFMA. Output f16 NHWC.
// (R8 version, unchanged)
// ---------------------------------------------------------------------------
__global__ __launch_bounds__(256, 4) void conv1_mfma(
    const float* __restrict__ g, const char* __restrict__ ws_w1,
    const float* __restrict__ gamma, const float* __restrict__ beta,
    const float* __restrict__ mean, const float* __restrict__ var,
    _Float16* __restrict__ xg)
{
    const int tx0 = blockIdx.x * 16, ty0 = blockIdx.y * 8, b = blockIdx.z;
    __shared__ __align__(16) _Float16 gl[2][17][18][32];   // 39168 B
    const int tid = threadIdx.x;

    const int gy0 = 2 * ty0 - 1;
    const int gxa0 = 2 * tx0 - 2;
    for (int i = tid; i < 17 * 32 * 17; i += 256) {
        int wr = i / 544; int rem = i - wr * 544;
        int cin = rem / 17; int c2 = rem - cin * 17;
        int gy = gy0 + wr;
        int gxa = gxa0 + 2 * c2;
        float2 v = make_float2(0.f, 0.f);
        if (gy >= 0 && gy < HG && gxa >= 0)
            v = *(const float2*)(g + ((size_t)(b * 32 + cin) * HG + gy) * WG + gxa);
        int slot = cin >> 3, elem = cin & 7;
        if (c2 > 0) {
            int wch = c2 - 1;
            gl[1][wr][wch][((slot ^ ((wch >> 1) & 3)) << 3) + elem] = (_Float16)v.x;
        }
        {
            int wch = c2;
            gl[0][wr][wch][((slot ^ ((wch >> 1) & 3)) << 3) + elem] = (_Float16)v.y;
        }
    }

    const int lane = tid & 63, w = tid >> 6;
    const int c = lane & 15, grp = lane >> 4;

    const _Float16* w1p = (const _Float16*)ws_w1 + lane * 8;
    half8 bf[4];
#pragma unroll
    for (int nt = 0; nt < 4; ++nt) bf[nt] = *(const half8*)(w1p + nt * 512);

    f32x4 zf = {0.f, 0.f, 0.f, 0.f};
    f32x4 acc[2][4];
#pragma unroll
    for (int mt = 0; mt < 2; ++mt)
#pragma unroll
        for (int nt = 0; nt < 4; ++nt) acc[mt][nt] = zf;

    __syncthreads();   // gl ready; no further barriers

#pragma unroll
    for (int s = 0; s < 9; ++s) {
        const int dy = s / 3, dx = s - dy * 3;
        const int par = dx & 1, dxh = dx >> 1;
        half8 af[2];
#pragma unroll
        for (int mt = 0; mt < 2; ++mt) {
            int wr = 2 * (2 * w + mt) + dy;
            int wch = c + dxh;
            af[mt] = *(const half8*)&gl[par][wr][wch][(grp ^ ((wch >> 1) & 3)) << 3];
        }
        const _Float16* wnext = w1p + (size_t)(s + 1) * 2048;
#pragma unroll
        for (int nt = 0; nt < 4; ++nt) {
            half8 cur = bf[nt];
            bf[nt] = *(const half8*)(wnext + nt * 512);   // s=8 overread harmless
            acc[0][nt] = __builtin_amdgcn_mfma_f32_16x16x32_f16(af[0], cur, acc[0][nt], 0, 0, 0);
            acc[1][nt] = __builtin_amdgcn_mfma_f32_16x16x32_f16(af[1], cur, acc[1][nt], 0, 0, 0);
        }
    }

#pragma unroll
    for (int nt = 0; nt < 4; ++nt) {
        int ch = nt * 16 + c;
        float mu = mean[ch], scv = rsqrtf(var[ch] + 1e-5f) * gamma[ch], bt = beta[ch];
#pragma unroll
        for (int mt = 0; mt < 2; ++mt) {
            int y = ty0 + 2 * w + mt;
#pragma unroll
            for (int r = 0; r < 4; ++r) {
                int x = tx0 + grp * 4 + r;
                float v = fmaxf((acc[mt][nt][r] - mu) * scv + bt, 0.f);
                xg[(((size_t)(b * H + y) * W + x) << 6) + ch] = (_Float16)v;
            }
        }
    }
}

// ---------------------------------------------------------------------------
// conv2 (3x3 s1 p1, 64->576) + softmax(9) + convex combine + pixel shuffle.
// PERSISTENT engine: 512 blocks (2/CU), tiles bid, bid+512, ... Per tile:
// 16x4 px, 4 waves (wave = ng, k-complete per lane -> lane-local softmax),
// Mt=4, register-direct B stream, ring-offset K order, no K-loop barriers,
// s_setprio around MFMA clusters, vectorized d8s-patch epilogue.
// CHANGE vs R17: ring loop back to #pragma unroll 2 (R13 pressure) to cut
// arch VGPRs 128->~112 so arch+AGPR <= 256 -> 2 waves/SIMD definitively.
// A/B disambiguates R16's gain: occupancy (expect 62-66) vs ILP (72-74).
// ---------------------------------------------------------------------------
__global__ __launch_bounds__(256, 2) void conv2_mfma(
    const _Float16* __restrict__ xg, const char* __restrict__ ws_c,
    const float* __restrict__ disp, float* __restrict__ out)
{
    __shared__ __align__(16) _Float16 xs[108 * 64];   // 6r x 18c x 64ch, 13824 B
    __shared__ __align__(16) float d8s[6 * 24];       // rows padded 18->24
    const int tid = threadIdx.x;
    const int lane = tid & 63, wid = tid >> 6;
    const int c = lane & 15, grp = lane >> 4;

    // this wave's weight stream: [18 s][9 k][1024B], lane slice = lane*16 B
    const _Float16* wp = (const _Float16*)ws_c + (size_t)wid * 82944 + lane * 8;

    half8 zero8;
#pragma unroll
    for (int j = 0; j < 8; ++j) zero8[j] = (_Float16)0.f;

    for (int tile = blockIdx.x; tile < 1600; tile += 512) {
        const int b   = tile / 200;
        const int rem = tile - b * 200;
        const int tyi = rem / 10;
        const int tx0 = (rem - tyi * 10) * 16, ty0 = tyi * 4;
        const int s0  = (tile * 7) % 18;

        __syncthreads();   // guard xs/d8s overwrite vs prior tile's readers

        // stage x window 6x18x64 f16, swizzled: 16B slot' = slot ^ (wp&7)
        for (int cidx = tid; cidx < 864; cidx += 256) {
            int wpx = cidx >> 3, slot = cidx & 7;
            int rr = wpx / 18, cc = wpx - rr * 18;
            int y = ty0 - 1 + rr, xc = tx0 - 1 + cc;
            half8 v = zero8;
            if (y >= 0 && y < H && xc >= 0 && xc < W)
                v = *(const half8*)(xg + (((size_t)(b * H + y) * W + xc) << 6) + slot * 8);
            *(half8*)&xs[wpx * 64 + (slot ^ (wpx & 7)) * 8] = v;
        }
        if (tid < 108) {
            int rr = tid / 18, cc = tid - rr * 18;
            int y = ty0 - 1 + rr, xc = tx0 - 1 + cc;
            float v = 0.f;
            if (y >= 0 && y < H && xc >= 0 && xc < W) v = 8.f * disp[(b * H + y) * W + xc];
            d8s[rr * 24 + cc] = v;
        }

        f32x4 zf = {0.f, 0.f, 0.f, 0.f};
        f32x4 acc[4][9];
#pragma unroll
        for (int m = 0; m < 4; ++m)
#pragma unroll
            for (int k = 0; k < 9; ++k) acc[m][k] = zf;

        half8 bf[9];
#pragma unroll
        for (int k = 0; k < 9; ++k)
            bf[k] = *(const half8*)(wp + (size_t)s0 * 4608 + k * 512);

        __syncthreads();   // xs, d8s ready

        int s = s0;
#pragma unroll 2
        for (int i = 0; i < 18; ++i) {
            int sn = s + 1; if (sn == 18) sn = 0;
            const int t = s >> 1;
            const int dy = t / 3, dx = t - dy * 3;
            const int aslot = (s & 1) * 4 + grp;
            half8 af[4];
#pragma unroll
            for (int mt = 0; mt < 4; ++mt) {
                int wrow = (mt + dy) * 18 + c + dx;
                af[mt] = *(const half8*)&xs[wrow * 64 + (aslot ^ (wrow & 7)) * 8];
            }
            const _Float16* wnext = wp + (size_t)sn * 4608;
            __builtin_amdgcn_s_setprio(1);
#pragma unroll
            for (int k = 0; k < 9; ++k) {
                half8 cur = bf[k];
                // prefetch ring-next step's fragment k (wrap load unused, valid)
                bf[k] = *(const half8*)(wnext + k * 512);
#pragma unroll
                for (int mt = 0; mt < 4; ++mt)
                    acc[mt][k] = __builtin_amdgcn_mfma_f32_16x16x32_f16(
                        af[mt], cur, acc[mt][k], 0, 0, 0);
            }
            __builtin_amdgcn_s_setprio(0);
            s = sn;
        }

        // epilogue: lane-local softmax; 3x6 d8s patch loaded once per mt
        const int ij = wid * 16 + c;
        const int oi = ij >> 3, oj = ij & 7;
        const int c0 = grp * 4;
#pragma unroll
        for (int mt = 0; mt < 4; ++mt) {
            float p[3][6];
#pragma unroll
            for (int ky = 0; ky < 3; ++ky) {
                float4 q0 = *(const float4*)&d8s[(mt + ky) * 24 + c0];
                float2 q1 = *(const float2*)&d8s[(mt + ky) * 24 + c0 + 4];
                p[ky][0] = q0.x; p[ky][1] = q0.y; p[ky][2] = q0.z; p[ky][3] = q0.w;
                p[ky][4] = q1.x; p[ky][5] = q1.y;
            }
#pragma unroll
            for (int r = 0; r < 4; ++r) {
                float mx = acc[mt][0][r];
#pragma unroll
                for (int k9 = 1; k9 < 9; ++k9) mx = fmaxf(mx, acc[mt][k9][r]);
                float sum = 0.f, up = 0.f;
#pragma unroll
                for (int k9 = 0; k9 < 9; ++k9) {
                    float e = __expf(acc[mt][k9][r] - mx);
                    sum += e; up += e * p[k9 / 3][r + k9 % 3];
                }
                int y = ty0 + mt, xc = tx0 + c0 + r;
                out[((size_t)(b * (8 * H) + y * 8 + oi)) * (size_t)(8 * W) + xc * 8 + oj] = up / sum;
            }
        }
    }
}

// ---------------------------------------------------------------------------
extern "C" void kernel_launch(void* const* d_in, const int* in_sizes, int n_in,
                              void* d_out, int out_size, void* d_ws, size_t ws_size,
                              hipStream_t stream)
{
    const float* guidance = (const float*)d_in[0];
    const float* disp     = (const float*)d_in[1];
    const float* conv1_w  = (const float*)d_in[2];
    const float* bn_gamma = (const float*)d_in[3];
    const float* bn_beta  = (const float*)d_in[4];
    const float* bn_mean  = (const float*)d_in[5];
    const float* bn_var   = (const float*)d_in[6];
    const float* conv2_w  = (const float*)d_in[7];
    float* out = (float*)d_out;
    char* ws = (char*)d_ws;
    _Float16* xg = (_Float16*)(ws + XG_OFF);

    prep<<<dim3((4 * 18 * 9 * 64 + 9 * 4 * 64 + 255) / 256), dim3(256), 0, stream>>>(
        conv1_w, conv2_w, ws);
    dim3 grid1(W / 16, H / 8, B_);   // (10, 10, 8)
    conv1_mfma<<<grid1, dim3(256), 0, stream>>>(
        guidance, ws + W1WS_OFF, bn_gamma, bn_beta, bn_mean, bn_var, xg);
    conv2_mfma<<<dim3(512), dim3(256), 0, stream>>>(
        xg, ws + CWS_OFF, disp, out);
}

// Round 19
// 105.202 us; speedup vs baseline: 1.0138x; 1.0138x over previous
//
#include <hip/hip_runtime.h>
#include <math.h>

typedef _Float16 half8 __attribute__((ext_vector_type(8)));
typedef float f32x4 __attribute__((ext_vector_type(4)));

// dims
constexpr int B_ = 8;
constexpr int HG = 160, WG = 320;          // guidance spatial
constexpr int H = 80, W = 160;             // x spatial
// ws layout (bytes)
constexpr size_t CWS_OFF  = 0;             // 4 ng * 165888 = 663552
constexpr size_t W1WS_OFF = 663552;        // 9 taps * 4096 = 36864
constexpr size_t XG_OFF   = 700416;        // 8*80*160*64*2 = 13107200

// ---------------------------------------------------------------------------
// prep: one thread per 16-B fragment slot -> fully coalesced half8 stores.
// (R18 version, unchanged)
// ---------------------------------------------------------------------------
__global__ __launch_bounds__(256) void prep(const float* __restrict__ w1,
                                            const float* __restrict__ w2,
                                            char* __restrict__ ws)
{
    int e = blockIdx.x * 256 + threadIdx.x;
    if (e < 4 * 18 * 9 * 64) {
        int l  = e & 63;
        int r  = e >> 6;           // (ng*18 + s)*9 + k
        int k  = r % 9;
        int s  = (r / 9) % 18;
        int ng = r / (9 * 18);
        int grp = l >> 4, nl = l & 15;
        int t = s >> 1, c5 = s & 1;
        int n = k * 64 + ng * 16 + nl;
        const float* src = w2 + ((size_t)n * 64 + c5 * 32 + grp * 8) * 9 + t;
        half8 v;
#pragma unroll
        for (int j = 0; j < 8; ++j) v[j] = (_Float16)src[j * 9];
        *(half8*)(ws + CWS_OFF + (size_t)ng * 165888
                  + (size_t)(s * 9 + k) * 1024 + l * 16) = v;
    } else if (e < 4 * 18 * 9 * 64 + 9 * 4 * 64) {
        int e2 = e - 4 * 18 * 9 * 64;
        int l  = e2 & 63;
        int nt = (e2 >> 6) & 3;
        int t  = e2 >> 8;
        int grp = l >> 4, nl = l & 15;
        int ch = nt * 16 + nl;
        const float* src = w1 + ((size_t)ch * 32 + grp * 8) * 9 + t;
        half8 v;
#pragma unroll
        for (int j = 0; j < 8; ++j) v[j] = (_Float16)src[j * 9];
        *(half8*)(ws + W1WS_OFF + (size_t)t * 4096 + nt * 1024 + l * 16) = v;
    }
}

// ---------------------------------------------------------------------------
// conv1 (3x3 s2 p1, 32->64) + BN + ReLU via MFMA. Output f16 NHWC.
// STAGING REWRITE vs R18: one thread per (wr, c2, cin-octet) -> 8 coalesced
// float2 loads (8 channels of the even/odd gx pair at gxa = 2*tx0-2+2*c2),
// register repack, TWO ds_write_b128 (was: per-element 2-B LDS stores).
//   gl[0][wr][wch] = g[gy0+wr][2*tx0-1+2*wch]  (odd gx, = v.y at c2=wch)
//   gl[1][wr][wch] = g[gy0+wr][2*tx0+2*wch]    (even gx, = v.x at c2=wch+1)
// MFMA loop and epilogue unchanged (verified mapping identical to R8).
// ---------------------------------------------------------------------------
__global__ __launch_bounds__(256, 4) void conv1_mfma(
    const float* __restrict__ g, const char* __restrict__ ws_w1,
    const float* __restrict__ gamma, const float* __restrict__ beta,
    const float* __restrict__ mean, const float* __restrict__ var,
    _Float16* __restrict__ xg)
{
    const int tx0 = blockIdx.x * 16, ty0 = blockIdx.y * 8, b = blockIdx.z;
    __shared__ __align__(16) _Float16 gl[2][17][18][32];   // 39168 B
    const int tid = threadIdx.x;

    const int gy0 = 2 * ty0 - 1;
    const int gxa0 = 2 * tx0 - 2;
    // 17 rows x 17 gx-pairs x 4 cin-octets = 1156 iters (4.5/thread)
    for (int i = tid; i < 17 * 17 * 4; i += 256) {
        int wr = i / 68; int rem = i - wr * 68;
        int slot = rem / 17, c2 = rem - slot * 17;
        int gy = gy0 + wr;
        int gxa = gxa0 + 2 * c2;
        const bool ok = (gy >= 0 && gy < HG && gxa >= 0);
        half8 ve, vo;
#pragma unroll
        for (int j = 0; j < 8; ++j) {
            float2 v = make_float2(0.f, 0.f);
            if (ok)
                v = *(const float2*)(g + ((size_t)(b * 32 + slot * 8 + j) * HG + gy) * WG + gxa);
            ve[j] = (_Float16)v.x;
            vo[j] = (_Float16)v.y;
        }
        if (c2 > 0)
            *(half8*)&gl[1][wr][c2 - 1][(slot ^ (((c2 - 1) >> 1) & 3)) << 3] = ve;
        *(half8*)&gl[0][wr][c2][(slot ^ ((c2 >> 1) & 3)) << 3] = vo;
    }

    const int lane = tid & 63, w = tid >> 6;
    const int c = lane & 15, grp = lane >> 4;

    const _Float16* w1p = (const _Float16*)ws_w1 + lane * 8;
    half8 bf[4];
#pragma unroll
    for (int nt = 0; nt < 4; ++nt) bf[nt] = *(const half8*)(w1p + nt * 512);

    f32x4 zf = {0.f, 0.f, 0.f, 0.f};
    f32x4 acc[2][4];
#pragma unroll
    for (int mt = 0; mt < 2; ++mt)
#pragma unroll
        for (int nt = 0; nt < 4; ++nt) acc[mt][nt] = zf;

    __syncthreads();   // gl ready; no further barriers

#pragma unroll
    for (int s = 0; s < 9; ++s) {
        const int dy = s / 3, dx = s - dy * 3;
        const int par = dx & 1, dxh = dx >> 1;
        half8 af[2];
#pragma unroll
        for (int mt = 0; mt < 2; ++mt) {
            int wr = 2 * (2 * w + mt) + dy;
            int wch = c + dxh;
            af[mt] = *(const half8*)&gl[par][wr][wch][(grp ^ ((wch >> 1) & 3)) << 3];
        }
        const _Float16* wnext = w1p + (size_t)(s + 1) * 2048;
#pragma unroll
        for (int nt = 0; nt < 4; ++nt) {
            half8 cur = bf[nt];
            bf[nt] = *(const half8*)(wnext + nt * 512);   // s=8 overread harmless
            acc[0][nt] = __builtin_amdgcn_mfma_f32_16x16x32_f16(af[0], cur, acc[0][nt], 0, 0, 0);
            acc[1][nt] = __builtin_amdgcn_mfma_f32_16x16x32_f16(af[1], cur, acc[1][nt], 0, 0, 0);
        }
    }

#pragma unroll
    for (int nt = 0; nt < 4; ++nt) {
        int ch = nt * 16 + c;
        float mu = mean[ch], scv = rsqrtf(var[ch] + 1e-5f) * gamma[ch], bt = beta[ch];
#pragma unroll
        for (int mt = 0; mt < 2; ++mt) {
            int y = ty0 + 2 * w + mt;
#pragma unroll
            for (int r = 0; r < 4; ++r) {
                int x = tx0 + grp * 4 + r;
                float v = fmaxf((acc[mt][nt][r] - mu) * scv + bt, 0.f);
                xg[(((size_t)(b * H + y) * W + x) << 6) + ch] = (_Float16)v;
            }
        }
    }
}

// ---------------------------------------------------------------------------
// conv2 (3x3 s1 p1, 64->576) + softmax(9) + convex combine + pixel shuffle.
// (R18 version, unchanged — persistent 512 blocks, 16x4 px / 4 waves,
// register-direct B, ring-offset K order, setprio MFMA clusters, unroll 2,
// vectorized d8s-patch epilogue. conv2 is at its structural fixed point.)
// ---------------------------------------------------------------------------
__global__ __launch_bounds__(256, 2) void conv2_mfma(
    const _Float16* __restrict__ xg, const char* __restrict__ ws_c,
    const float* __restrict__ disp, float* __restrict__ out)
{
    __shared__ __align__(16) _Float16 xs[108 * 64];   // 6r x 18c x 64ch, 13824 B
    __shared__ __align__(16) float d8s[6 * 24];       // rows padded 18->24
    const int tid = threadIdx.x;
    const int lane = tid & 63, wid = tid >> 6;
    const int c = lane & 15, grp = lane >> 4;

    // this wave's weight stream: [18 s][9 k][1024B], lane slice = lane*16 B
    const _Float16* wp = (const _Float16*)ws_c + (size_t)wid * 82944 + lane * 8;

    half8 zero8;
#pragma unroll
    for (int j = 0; j < 8; ++j) zero8[j] = (_Float16)0.f;

    for (int tile = blockIdx.x; tile < 1600; tile += 512) {
        const int b   = tile / 200;
        const int rem = tile - b * 200;
        const int tyi = rem / 10;
        const int tx0 = (rem - tyi * 10) * 16, ty0 = tyi * 4;
        const int s0  = (tile * 7) % 18;

        __syncthreads();   // guard xs/d8s overwrite vs prior tile's readers

        // stage x window 6x18x64 f16, swizzled: 16B slot' = slot ^ (wp&7)
        for (int cidx = tid; cidx < 864; cidx += 256) {
            int wpx = cidx >> 3, slot = cidx & 7;
            int rr = wpx / 18, cc = wpx - rr * 18;
            int y = ty0 - 1 + rr, xc = tx0 - 1 + cc;
            half8 v = zero8;
            if (y >= 0 && y < H && xc >= 0 && xc < W)
                v = *(const half8*)(xg + (((size_t)(b * H + y) * W + xc) << 6) + slot * 8);
            *(half8*)&xs[wpx * 64 + (slot ^ (wpx & 7)) * 8] = v;
        }
        if (tid < 108) {
            int rr = tid / 18, cc = tid - rr * 18;
            int y = ty0 - 1 + rr, xc = tx0 - 1 + cc;
            float v = 0.f;
            if (y >= 0 && y < H && xc >= 0 && xc < W) v = 8.f * disp[(b * H + y) * W + xc];
            d8s[rr * 24 + cc] = v;
        }

        f32x4 zf = {0.f, 0.f, 0.f, 0.f};
        f32x4 acc[4][9];
#pragma unroll
        for (int m = 0; m < 4; ++m)
#pragma unroll
            for (int k = 0; k < 9; ++k) acc[m][k] = zf;

        half8 bf[9];
#pragma unroll
        for (int k = 0; k < 9; ++k)
            bf[k] = *(const half8*)(wp + (size_t)s0 * 4608 + k * 512);

        __syncthreads();   // xs, d8s ready

        int s = s0;
#pragma unroll 2
        for (int i = 0; i < 18; ++i) {
            int sn = s + 1; if (sn == 18) sn = 0;
            const int t = s >> 1;
            const int dy = t / 3, dx = t - dy * 3;
            const int aslot = (s & 1) * 4 + grp;
            half8 af[4];
#pragma unroll
            for (int mt = 0; mt < 4; ++mt) {
                int wrow = (mt + dy) * 18 + c + dx;
                af[mt] = *(const half8*)&xs[wrow * 64 + (aslot ^ (wrow & 7)) * 8];
            }
            const _Float16* wnext = wp + (size_t)sn * 4608;
            __builtin_amdgcn_s_setprio(1);
#pragma unroll
            for (int k = 0; k < 9; ++k) {
                half8 cur = bf[k];
                // prefetch ring-next step's fragment k (wrap load unused, valid)
                bf[k] = *(const half8*)(wnext + k * 512);
#pragma unroll
                for (int mt = 0; mt < 4; ++mt)
                    acc[mt][k] = __builtin_amdgcn_mfma_f32_16x16x32_f16(
                        af[mt], cur, acc[mt][k], 0, 0, 0);
            }
            __builtin_amdgcn_s_setprio(0);
            s = sn;
        }

        // epilogue: lane-local softmax; 3x6 d8s patch loaded once per mt
        const int ij = wid * 16 + c;
        const int oi = ij >> 3, oj = ij & 7;
        const int c0 = grp * 4;
#pragma unroll
        for (int mt = 0; mt < 4; ++mt) {
            float p[3][6];
#pragma unroll
            for (int ky = 0; ky < 3; ++ky) {
                float4 q0 = *(const float4*)&d8s[(mt + ky) * 24 + c0];
                float2 q1 = *(const float2*)&d8s[(mt + ky) * 24 + c0 + 4];
                p[ky][0] = q0.x; p[ky][1] = q0.y; p[ky][2] = q0.z; p[ky][3] = q0.w;
                p[ky][4] = q1.x; p[ky][5] = q1.y;
            }
#pragma unroll
            for (int r = 0; r < 4; ++r) {
                float mx = acc[mt][0][r];
#pragma unroll
                for (int k9 = 1; k9 < 9; ++k9) mx = fmaxf(mx, acc[mt][k9][r]);
                float sum = 0.f, up = 0.f;
#pragma unroll
                for (int k9 = 0; k9 < 9; ++k9) {
                    float e = __expf(acc[mt][k9][r] - mx);
                    sum += e; up += e * p[k9 / 3][r + k9 % 3];
                }
                int y = ty0 + mt, xc = tx0 + c0 + r;
                out[((size_t)(b * (8 * H) + y * 8 + oi)) * (size_t)(8 * W) + xc * 8 + oj] = up / sum;
            }
        }
    }
}

// ---------------------------------------------------------------------------
extern "C" void kernel_launch(void* const* d_in, const int* in_sizes, int n_in,
                              void* d_out, int out_size, void* d_ws, size_t ws_size,
                              hipStream_t stream)
{
    const float* guidance = (const float*)d_in[0];
    const float* disp     = (const float*)d_in[1];
    const float* conv1_w  = (const float*)d_in[2];
    const float* bn_gamma = (const float*)d_in[3];
    const float* bn_beta  = (const float*)d_in[4];
    const float* bn_mean  = (const float*)d_in[5];
    const float* bn_var   = (const float*)d_in[6];
    const float* conv2_w  = (const float*)d_in[7];
    float* out = (float*)d_out;
    char* ws = (char*)d_ws;
    _Float16* xg = (_Float16*)(ws + XG_OFF);

    prep<<<dim3((4 * 18 * 9 * 64 + 9 * 4 * 64 + 255) / 256), dim3(256), 0, stream>>>(
        conv1_w, conv2_w, ws);
    dim3 grid1(W / 16, H / 8, B_);   // (10, 10, 8)
    conv1_mfma<<<grid1, dim3(256), 0, stream>>>(
        guidance, ws + W1WS_OFF, bn_gamma, bn_beta, bn_mean, bn_var, xg);
    conv2_mfma<<<dim3(512), dim3(256), 0, stream>>>(
        xg, ws + CWS_OFF, disp, out);
}

// Round 20
// 102.883 us; speedup vs baseline: 1.0367x; 1.0225x over previous
//
#include <hip/hip_runtime.h>
#include <math.h>

typedef _Float16 half8 __attribute__((ext_vector_type(8)));
typedef float f32x4 __attribute__((ext_vector_type(4)));

// dims
constexpr int B_ = 8;
constexpr int HG = 160, WG = 320;          // guidance spatial
constexpr int H = 80, W = 160;             // x spatial
// ws layout (bytes)
constexpr size_t CWS_OFF  = 0;             // 4 ng * 165888 = 663552
constexpr size_t W1WS_OFF = 663552;        // 9 taps * 4096 = 36864
constexpr size_t XG_OFF   = 700416;        // 8*80*160*64*2 = 13107200

// ---------------------------------------------------------------------------
// prep: one thread per 16-B fragment slot -> fully coalesced half8 stores.
// (R18 version, unchanged)
// ---------------------------------------------------------------------------
__global__ __launch_bounds__(256) void prep(const float* __restrict__ w1,
                                            const float* __restrict__ w2,
                                            char* __restrict__ ws)
{
    int e = blockIdx.x * 256 + threadIdx.x;
    if (e < 4 * 18 * 9 * 64) {
        int l  = e & 63;
        int r  = e >> 6;           // (ng*18 + s)*9 + k
        int k  = r % 9;
        int s  = (r / 9) % 18;
        int ng = r / (9 * 18);
        int grp = l >> 4, nl = l & 15;
        int t = s >> 1, c5 = s & 1;
        int n = k * 64 + ng * 16 + nl;
        const float* src = w2 + ((size_t)n * 64 + c5 * 32 + grp * 8) * 9 + t;
        half8 v;
#pragma unroll
        for (int j = 0; j < 8; ++j) v[j] = (_Float16)src[j * 9];
        *(half8*)(ws + CWS_OFF + (size_t)ng * 165888
                  + (size_t)(s * 9 + k) * 1024 + l * 16) = v;
    } else if (e < 4 * 18 * 9 * 64 + 9 * 4 * 64) {
        int e2 = e - 4 * 18 * 9 * 64;
        int l  = e2 & 63;
        int nt = (e2 >> 6) & 3;
        int t  = e2 >> 8;
        int grp = l >> 4, nl = l & 15;
        int ch = nt * 16 + nl;
        const float* src = w1 + ((size_t)ch * 32 + grp * 8) * 9 + t;
        half8 v;
#pragma unroll
        for (int j = 0; j < 8; ++j) v[j] = (_Float16)src[j * 9];
        *(half8*)(ws + W1WS_OFF + (size_t)t * 4096 + nt * 1024 + l * 16) = v;
    }
}

// ---------------------------------------------------------------------------
// conv1 (3x3 s2 p1, 32->64) + BN + ReLU via MFMA. Output f16 NHWC.
// (R19 version, unchanged)
// ---------------------------------------------------------------------------
__global__ __launch_bounds__(256, 4) void conv1_mfma(
    const float* __restrict__ g, const char* __restrict__ ws_w1,
    const float* __restrict__ gamma, const float* __restrict__ beta,
    const float* __restrict__ mean, const float* __restrict__ var,
    _Float16* __restrict__ xg)
{
    const int tx0 = blockIdx.x * 16, ty0 = blockIdx.y * 8, b = blockIdx.z;
    __shared__ __align__(16) _Float16 gl[2][17][18][32];   // 39168 B
    const int tid = threadIdx.x;

    const int gy0 = 2 * ty0 - 1;
    const int gxa0 = 2 * tx0 - 2;
    for (int i = tid; i < 17 * 17 * 4; i += 256) {
        int wr = i / 68; int rem = i - wr * 68;
        int slot = rem / 17, c2 = rem - slot * 17;
        int gy = gy0 + wr;
        int gxa = gxa0 + 2 * c2;
        const bool ok = (gy >= 0 && gy < HG && gxa >= 0);
        half8 ve, vo;
#pragma unroll
        for (int j = 0; j < 8; ++j) {
            float2 v = make_float2(0.f, 0.f);
            if (ok)
                v = *(const float2*)(g + ((size_t)(b * 32 + slot * 8 + j) * HG + gy) * WG + gxa);
            ve[j] = (_Float16)v.x;
            vo[j] = (_Float16)v.y;
        }
        if (c2 > 0)
            *(half8*)&gl[1][wr][c2 - 1][(slot ^ (((c2 - 1) >> 1) & 3)) << 3] = ve;
        *(half8*)&gl[0][wr][c2][(slot ^ ((c2 >> 1) & 3)) << 3] = vo;
    }

    const int lane = tid & 63, w = tid >> 6;
    const int c = lane & 15, grp = lane >> 4;

    const _Float16* w1p = (const _Float16*)ws_w1 + lane * 8;
    half8 bf[4];
#pragma unroll
    for (int nt = 0; nt < 4; ++nt) bf[nt] = *(const half8*)(w1p + nt * 512);

    f32x4 zf = {0.f, 0.f, 0.f, 0.f};
    f32x4 acc[2][4];
#pragma unroll
    for (int mt = 0; mt < 2; ++mt)
#pragma unroll
        for (int nt = 0; nt < 4; ++nt) acc[mt][nt] = zf;

    __syncthreads();   // gl ready; no further barriers

#pragma unroll
    for (int s = 0; s < 9; ++s) {
        const int dy = s / 3, dx = s - dy * 3;
        const int par = dx & 1, dxh = dx >> 1;
        half8 af[2];
#pragma unroll
        for (int mt = 0; mt < 2; ++mt) {
            int wr = 2 * (2 * w + mt) + dy;
            int wch = c + dxh;
            af[mt] = *(const half8*)&gl[par][wr][wch][(grp ^ ((wch >> 1) & 3)) << 3];
        }
        const _Float16* wnext = w1p + (size_t)(s + 1) * 2048;
#pragma unroll
        for (int nt = 0; nt < 4; ++nt) {
            half8 cur = bf[nt];
            bf[nt] = *(const half8*)(wnext + nt * 512);   // s=8 overread harmless
            acc[0][nt] = __builtin_amdgcn_mfma_f32_16x16x32_f16(af[0], cur, acc[0][nt], 0, 0, 0);
            acc[1][nt] = __builtin_amdgcn_mfma_f32_16x16x32_f16(af[1], cur, acc[1][nt], 0, 0, 0);
        }
    }

#pragma unroll
    for (int nt = 0; nt < 4; ++nt) {
        int ch = nt * 16 + c;
        float mu = mean[ch], scv = rsqrtf(var[ch] + 1e-5f) * gamma[ch], bt = beta[ch];
#pragma unroll
        for (int mt = 0; mt < 2; ++mt) {
            int y = ty0 + 2 * w + mt;
#pragma unroll
            for (int r = 0; r < 4; ++r) {
                int x = tx0 + grp * 4 + r;
                float v = fmaxf((acc[mt][nt][r] - mu) * scv + bt, 0.f);
                xg[(((size_t)(b * H + y) * W + x) << 6) + ch] = (_Float16)v;
            }
        }
    }
}

// ---------------------------------------------------------------------------
// conv2 (3x3 s1 p1, 64->576) + softmax(9) + convex combine + pixel shuffle.
// PERSISTENT engine (R18) + T14 async-STAGE split: next tile's xs/d8s global
// loads are issued right after the K-loop and their latency hides under the
// softmax epilogue; the loop-top stage phase is then only ds_write_b128s
// (LDS addresses are tile-independent, so no deferred coords needed).
// Staged regs (4x half8 + 1 float) are dead across the K-loop -> peak
// K-loop VGPR pressure unchanged.
// ---------------------------------------------------------------------------
__global__ __launch_bounds__(256, 2) void conv2_mfma(
    const _Float16* __restrict__ xg, const char* __restrict__ ws_c,
    const float* __restrict__ disp, float* __restrict__ out)
{
    __shared__ __align__(16) _Float16 xs[108 * 64];   // 6r x 18c x 64ch, 13824 B
    __shared__ __align__(16) float d8s[6 * 24];       // rows padded 18->24
    const int tid = threadIdx.x;
    const int lane = tid & 63, wid = tid >> 6;
    const int c = lane & 15, grp = lane >> 4;

    // this wave's weight stream: [18 s][9 k][1024B], lane slice = lane*16 B
    const _Float16* wp = (const _Float16*)ws_c + (size_t)wid * 82944 + lane * 8;

    half8 zero8;
#pragma unroll
    for (int j = 0; j < 8; ++j) zero8[j] = (_Float16)0.f;

    half8 stg[4];   // staged xs slots (cidx = tid + j*256, valid if < 864)
    float dstg = 0.f;

    // prefetch tile's window into registers (loads only; no LDS writes)
    auto prefetch = [&](int tile) {
        const int b   = tile / 200;
        const int rem = tile - b * 200;
        const int tyi = rem / 10;
        const int tx0 = (rem - tyi * 10) * 16, ty0 = tyi * 4;
#pragma unroll
        for (int j = 0; j < 4; ++j) {
            int cidx = tid + j * 256;
            if (cidx < 864) {
                int wpx = cidx >> 3, slot = cidx & 7;
                int rr = wpx / 18, cc = wpx - rr * 18;
                int y = ty0 - 1 + rr, xc = tx0 - 1 + cc;
                half8 v = zero8;
                if (y >= 0 && y < H && xc >= 0 && xc < W)
                    v = *(const half8*)(xg + (((size_t)(b * H + y) * W + xc) << 6) + slot * 8);
                stg[j] = v;
            }
        }
        if (tid < 108) {
            int rr = tid / 18, cc = tid - rr * 18;
            int y = ty0 - 1 + rr, xc = tx0 - 1 + cc;
            dstg = (y >= 0 && y < H && xc >= 0 && xc < W)
                 ? 8.f * disp[(b * H + y) * W + xc] : 0.f;
        }
    };

    prefetch(blockIdx.x);   // first tile

    for (int tile = blockIdx.x; tile < 1600; tile += 512) {
        const int b   = tile / 200;
        const int rem = tile - b * 200;
        const int tyi = rem / 10;
        const int tx0 = (rem - tyi * 10) * 16, ty0 = tyi * 4;
        const int s0  = (tile * 7) % 18;

        __syncthreads();   // prior tile's xs/d8s readers done

        // write staged regs -> LDS (addresses tile-independent)
#pragma unroll
        for (int j = 0; j < 4; ++j) {
            int cidx = tid + j * 256;
            if (cidx < 864) {
                int wpx = cidx >> 3, slot = cidx & 7;
                *(half8*)&xs[wpx * 64 + (slot ^ (wpx & 7)) * 8] = stg[j];
            }
        }
        if (tid < 108) {
            int rr = tid / 18, cc = tid - rr * 18;
            d8s[rr * 24 + cc] = dstg;
        }

        f32x4 zf = {0.f, 0.f, 0.f, 0.f};
        f32x4 acc[4][9];
#pragma unroll
        for (int m = 0; m < 4; ++m)
#pragma unroll
            for (int k = 0; k < 9; ++k) acc[m][k] = zf;

        half8 bf[9];
#pragma unroll
        for (int k = 0; k < 9; ++k)
            bf[k] = *(const half8*)(wp + (size_t)s0 * 4608 + k * 512);

        __syncthreads();   // xs, d8s ready

        int s = s0;
#pragma unroll 2
        for (int i = 0; i < 18; ++i) {
            int sn = s + 1; if (sn == 18) sn = 0;
            const int t = s >> 1;
            const int dy = t / 3, dx = t - dy * 3;
            const int aslot = (s & 1) * 4 + grp;
            half8 af[4];
#pragma unroll
            for (int mt = 0; mt < 4; ++mt) {
                int wrow = (mt + dy) * 18 + c + dx;
                af[mt] = *(const half8*)&xs[wrow * 64 + (aslot ^ (wrow & 7)) * 8];
            }
            const _Float16* wnext = wp + (size_t)sn * 4608;
            __builtin_amdgcn_s_setprio(1);
#pragma unroll
            for (int k = 0; k < 9; ++k) {
                half8 cur = bf[k];
                // prefetch ring-next step's fragment k (wrap load unused, valid)
                bf[k] = *(const half8*)(wnext + k * 512);
#pragma unroll
                for (int mt = 0; mt < 4; ++mt)
                    acc[mt][k] = __builtin_amdgcn_mfma_f32_16x16x32_f16(
                        af[mt], cur, acc[mt][k], 0, 0, 0);
            }
            __builtin_amdgcn_s_setprio(0);
            s = sn;
        }

        // T14: issue next tile's loads now; latency hides under the epilogue
        if (tile + 512 < 1600) prefetch(tile + 512);

        // epilogue: lane-local softmax; 3x6 d8s patch loaded once per mt
        const int ij = wid * 16 + c;
        const int oi = ij >> 3, oj = ij & 7;
        const int c0 = grp * 4;
#pragma unroll
        for (int mt = 0; mt < 4; ++mt) {
            float p[3][6];
#pragma unroll
            for (int ky = 0; ky < 3; ++ky) {
                float4 q0 = *(const float4*)&d8s[(mt + ky) * 24 + c0];
                float2 q1 = *(const float2*)&d8s[(mt + ky) * 24 + c0 + 4];
                p[ky][0] = q0.x; p[ky][1] = q0.y; p[ky][2] = q0.z; p[ky][3] = q0.w;
                p[ky][4] = q1.x; p[ky][5] = q1.y;
            }
#pragma unroll
            for (int r = 0; r < 4; ++r) {
                float mx = acc[mt][0][r];
#pragma unroll
                for (int k9 = 1; k9 < 9; ++k9) mx = fmaxf(mx, acc[mt][k9][r]);
                float sum = 0.f, up = 0.f;
#pragma unroll
                for (int k9 = 0; k9 < 9; ++k9) {
                    float e = __expf(acc[mt][k9][r] - mx);
                    sum += e; up += e * p[k9 / 3][r + k9 % 3];
                }
                int y = ty0 + mt, xc = tx0 + c0 + r;
                out[((size_t)(b * (8 * H) + y * 8 + oi)) * (size_t)(8 * W) + xc * 8 + oj] = up / sum;
            }
        }
    }
}

// ---------------------------------------------------------------------------
extern "C" void kernel_launch(void* const* d_in, const int* in_sizes, int n_in,
                              void* d_out, int out_size, void* d_ws, size_t ws_size,
                              hipStream_t stream)
{
    const float* guidance = (const float*)d_in[0];
    const float* disp     = (const float*)d_in[1];
    const float* conv1_w  = (const float*)d_in[2];
    const float* bn_gamma = (const float*)d_in[3];
    const float* bn_beta  = (const float*)d_in[4];
    const float* bn_mean  = (const float*)d_in[5];
    const float* bn_var   = (const float*)d_in[6];
    const float* conv2_w  = (const float*)d_in[7];
    float* out = (float*)d_out;
    char* ws = (char*)d_ws;
    _Float16* xg = (_Float16*)(ws + XG_OFF);

    prep<<<dim3((4 * 18 * 9 * 64 + 9 * 4 * 64 + 255) / 256), dim3(256), 0, stream>>>(
        conv1_w, conv2_w, ws);
    dim3 grid1(W / 16, H / 8, B_);   // (10, 10, 8)
    conv1_mfma<<<grid1, dim3(256), 0, stream>>>(
        guidance, ws + W1WS_OFF, bn_gamma, bn_beta, bn_mean, bn_var, xg);
    conv2_mfma<<<dim3(512), dim3(256), 0, stream>>>(
        xg, ws + CWS_OFF, disp, out);
}